// Round 10
// baseline (208.813 us; speedup 1.0000x reference)
//
#include <hip/hip_runtime.h>
#include <hip/hip_bf16.h>
#include <cfloat>

// B=32, N=2048 -> BN=65536 rows, D=128, K=1024 codes
#define DIM 128
#define NCODES 1024
#define MTILE 128            // rows per row-tile = 4 waves x 32 rows
#define ROWS_PER_WAVE 32
#define NSUB 2               // 16-row M-subtiles per wave
#define KSTEPS 4             // K=128 / 32
#define NKB 2                // K-split: blocks per row-tile
#define KB_CODES (NCODES / NKB)            // 512 codes per block
#define CODES_PER_STEP 16
#define NSTEPS_BLK (KB_CODES / CODES_PER_STEP)  // 32 steps per block
#define GSTEPS (NCODES / CODES_PER_STEP)        // 64 global steps
#define PART_HALVES 2048     // hi (or lo) halves per 16-code step block (4 KB)
#define STEP_HALVES 4096     // hi+lo per step = 8 KB
#define NROWTILES 512
#define LOSS_SCALE (12.5f / 8388608.0f)

typedef _Float16 f16x8 __attribute__((ext_vector_type(8)));
typedef float f32x4 __attribute__((ext_vector_type(4)));
typedef unsigned long long u64;

// prep: E (fp32) -> f16 hi/lo split in MFMA-fragment chunk order (staging
// copies and ds_read_b128 fragment reads lane-consecutive = conflict-free),
// enorm = ||E_k||^2. Also initializes winners (all-ones for atomicMin),
// tickets (0) and loss (0) -- folds r9's hipMemsetAsync into this dispatch.
__global__ __launch_bounds__(128) void prep_kernel(const float* __restrict__ E,
                                                   _Float16* __restrict__ Es,
                                                   float* __restrict__ enorm,
                                                   u64* __restrict__ winners,
                                                   int* __restrict__ tickets,
                                                   float* __restrict__ loss) {
    const int code = blockIdx.x;
    const int d = threadIdx.x;
    const int gid = code * 128 + d;
    if (gid == 0) *loss = 0.f;
    if (gid < 65536) winners[gid] = ~0ull;        // covers BN rows
    if (gid < NROWTILES) tickets[gid] = 0;
    float e = E[code * DIM + d];
    _Float16 h = (_Float16)e;
    _Float16 l = (_Float16)(e - (float)h);
    const int stg = code >> 4, m16 = code & 15;
    const int ks = d >> 5, quad = (d >> 3) & 3, j = d & 7;
    const int chunk = ks * 64 + quad * 16 + m16;  // 256 chunks per part
    const size_t base = (size_t)stg * STEP_HALVES + (size_t)chunk * 8 + j;
    Es[base] = h;
    Es[base + PART_HALVES] = l;
    float sq = e * e;
#pragma unroll
    for (int off = 32; off > 0; off >>= 1) sq += __shfl_down(sq, off, 64);
    __shared__ float s2[2];
    if ((d & 63) == 0) s2[d >> 6] = sq;
    __syncthreads();
    if (d == 0) enorm[code] = s2[0] + s2[1];
}

__device__ __forceinline__ unsigned ord_f32(float f) {
    unsigned u = __float_as_uint(f);
    return (u & 0x80000000u) ? ~u : (u | 0x80000000u);
}

// MFMA dist + argmin (K-split, packed atomicMin merge) + fused finish:
// the LAST twin block per row-tile (device-scope ticket) decodes winners,
// gathers z_q and adds the dist-part of the loss -- no separate finish
// kernel, no winners memset (r9 post-mortem: +2 dispatches cost ~20 us and
// occupancy never rose because 35 KB LDS caps co-residency at 2 blocks/CU).
// This round: 19 KB LDS (16-code steps) to unstick blocks/CU.
// Key = ordered(dist)<<32 | index: dist bits deterministic per (row,code)
// => min key == (min dist, min index) == jnp first-index rule.
// r3 lesson: no runtime-indexed register arrays. r5: stay on (256,2).
__global__ __launch_bounds__(256, 2) void vq_kernel(const float* __restrict__ z,
                                                    const _Float16* __restrict__ Es,
                                                    const float* __restrict__ enorm,
                                                    u64* __restrict__ winners,
                                                    int* __restrict__ tickets,
                                                    const float* __restrict__ E,
                                                    float* __restrict__ out,
                                                    float* __restrict__ loss) {
    const int t = threadIdx.x;
    const int lane = t & 63;
    const int wave = t >> 6;     // row-wave: rows [wave*32, wave*32+32)
    const int m16 = lane & 15;   // A row within subtile / B,C code col
    const int quad = lane >> 4;  // k-group for A/B; row-group for C
    const int rowtile = blockIdx.x >> 1;  // twins adjacent -> z reads L2-shared
    const int khalf = blockIdx.x & 1;

    __shared__ _Float16 s_b[2][STEP_HALVES];  // 2 x 8 KB double buffer
    __shared__ float s_enorm[KB_CODES];       // this half's 512 norms, 2 KB
    __shared__ float s_znorm[MTILE];          // 0.5 KB
    __shared__ int s_ind[MTILE];              // 0.5 KB (finish phase)
    __shared__ float s_wsum[4];
    __shared__ int s_ticket;

    for (int i = t; i < KB_CODES; i += 256) s_enorm[i] = enorm[khalf * KB_CODES + i];

    // ---- A fragments: wave's 32 rows, K=128, scaled by -2, f16 hi/lo split.
    // A layout (16x16x32): lane holds A[m=lane&15][k=quad*8+j], j=0..7.
    f16x8 Ahi[NSUB][KSTEPS], Alo[NSUB][KSTEPS];
    float znp[NSUB] = {0.f, 0.f};
    const int rowbase = rowtile * MTILE + wave * ROWS_PER_WAVE;
#pragma unroll
    for (int s = 0; s < NSUB; ++s) {
        const int row = rowbase + s * 16 + m16;
        const float* zp = z + (size_t)row * DIM + quad * 8;
#pragma unroll
        for (int ks = 0; ks < KSTEPS; ++ks) {
            float4 v0 = *(const float4*)(zp + ks * 32);
            float4 v1 = *(const float4*)(zp + ks * 32 + 4);
            float zv[8] = {v0.x, v0.y, v0.z, v0.w, v1.x, v1.y, v1.z, v1.w};
#pragma unroll
            for (int j = 0; j < 8; ++j) {
                znp[s] = fmaf(zv[j], zv[j], znp[s]);
                float tt = -2.f * zv[j];
                _Float16 h = (_Float16)tt;
                Ahi[s][ks][j] = h;
                Alo[s][ks][j] = (_Float16)(tt - (float)h);
            }
        }
    }
#pragma unroll
    for (int s = 0; s < NSUB; ++s) {
        float v = znp[s];
        v += __shfl_xor(v, 16, 64);
        v += __shfl_xor(v, 32, 64);
        if (quad == 0) s_znorm[wave * ROWS_PER_WAVE + s * 16 + m16] = v;
    }

    float bestv[NSUB][4];
    int besti[NSUB][4];
#pragma unroll
    for (int s = 0; s < NSUB; ++s)
#pragma unroll
        for (int r = 0; r < 4; ++r) {
            bestv[s][r] = FLT_MAX;
            besti[s][r] = 0;
        }

    // Stage global step STG's 8 KB tile: 512 16B chunks; global contiguous,
    // LDS lane-consecutive (conflict-free). 2 chunks per thread.
#define STAGE(STG, B)                                                \
    {                                                                \
        const _Float16* src = Es + (size_t)(STG)*STEP_HALVES;        \
        _Pragma("unroll") for (int c = 0; c < 2; ++c) {              \
            const int idx = t + c * 256;                             \
            *(f16x8*)&s_b[B][(size_t)idx * 8] =                      \
                *(const f16x8*)(src + (size_t)idx * 8);              \
        }                                                            \
    }

    const int stg0 = khalf * NSTEPS_BLK;
    STAGE(stg0, 0)
    __syncthreads();

    // khalf==0 blocks contribute sum(znorm) (ordered by the barrier above)
    if (khalf == 0 && wave == 0) {
        float lp = s_znorm[lane] + s_znorm[lane + 64];
#pragma unroll
        for (int off = 32; off > 0; off >>= 1) lp += __shfl_down(lp, off, 64);
        if (lane == 0) atomicAdd(loss, lp * LOSS_SCALE);
    }

    int buf = 0;
    for (int st = 0; st < NSTEPS_BLK; ++st) {
        if (st + 1 < NSTEPS_BLK) STAGE(stg0 + st + 1, buf ^ 1)
        const _Float16* bh = s_b[buf];
        const _Float16* bl = s_b[buf] + PART_HALVES;
        f16x8 Bh[KSTEPS], Bl[KSTEPS];
#pragma unroll
        for (int ks = 0; ks < KSTEPS; ++ks) {
            const int chunk = ks * 64 + lane;  // lane-consecutive, conflict-free
            Bh[ks] = *(const f16x8*)(bh + (size_t)chunk * 8);
            Bl[ks] = *(const f16x8*)(bl + (size_t)chunk * 8);
        }
        f32x4 acc_hh[NSUB], acc_c[NSUB];
#pragma unroll
        for (int s = 0; s < NSUB; ++s) {
            acc_hh[s] = (f32x4){0.f, 0.f, 0.f, 0.f};
            acc_c[s] = (f32x4){0.f, 0.f, 0.f, 0.f};
        }
#pragma unroll
        for (int ks = 0; ks < KSTEPS; ++ks)
#pragma unroll
            for (int s = 0; s < NSUB; ++s) {
                acc_c[s] = __builtin_amdgcn_mfma_f32_16x16x32_f16(Ahi[s][ks], Bl[ks], acc_c[s], 0, 0, 0);
                acc_c[s] = __builtin_amdgcn_mfma_f32_16x16x32_f16(Alo[s][ks], Bh[ks], acc_c[s], 0, 0, 0);
                acc_hh[s] = __builtin_amdgcn_mfma_f32_16x16x32_f16(Ahi[s][ks], Bh[ks], acc_hh[s], 0, 0, 0);
            }
        const int nloc = st * CODES_PER_STEP + m16;
        const float e = s_enorm[nloc];
        const int n = khalf * KB_CODES + nloc;  // global code index
        // C layout: col = lane&15 (code), row = quad*4 + r
#pragma unroll
        for (int s = 0; s < NSUB; ++s)
#pragma unroll
            for (int r = 0; r < 4; ++r) {
                float d = (acc_hh[s][r] + acc_c[s][r]) + e;
                if (d < bestv[s][r]) {  // strict <, ascending n => first-index
                    bestv[s][r] = d;
                    besti[s][r] = n;
                }
            }
        __syncthreads();
        buf ^= 1;
    }
#undef STAGE

    // ---- in-wave argmin across the 16 m16-lanes (lexicographic (v,i))
#pragma unroll
    for (int s = 0; s < NSUB; ++s)
#pragma unroll
        for (int r = 0; r < 4; ++r) {
            float v = bestv[s][r];
            int i = besti[s][r];
#pragma unroll
            for (int m = 1; m <= 8; m <<= 1) {
                float ov = __shfl_xor(v, m, 64);
                int oi = __shfl_xor(i, m, 64);
                if (ov < v || (ov == v && oi < i)) {
                    v = ov;
                    i = oi;
                }
            }
            bestv[s][r] = v;
            besti[s][r] = i;
        }

    // ---- cross-block merge: packed device-scope atomicMin per row
    if (m16 == 0) {
#pragma unroll
        for (int s = 0; s < NSUB; ++s)
#pragma unroll
            for (int r = 0; r < 4; ++r) {
                const int row = rowbase + s * 16 + quad * 4 + r;
                u64 key = ((u64)ord_f32(bestv[s][r]) << 32) | (unsigned)besti[s][r];
                atomicMin(&winners[row], key);
            }
    }

    // ---- fused finish: last twin block per row-tile gathers + dist-loss
    __syncthreads();
    __threadfence();  // make our atomicMins visible before taking the ticket
    if (t == 0) s_ticket = atomicAdd(&tickets[rowtile], 1);
    __syncthreads();
    if (s_ticket != NKB - 1) return;

    const int row0 = rowtile * MTILE;
    float lp = 0.f;
    if (t < MTILE) {
        // atomic read (min with MAX = no-op) -- coherent view of both twins
        u64 w = atomicMin(&winners[row0 + t], ~0ull);
        s_ind[t] = (int)(unsigned)w;
        unsigned ou = (unsigned)(w >> 32);
        unsigned bits = (ou & 0x80000000u) ? (ou ^ 0x80000000u) : ~ou;
        lp = __uint_as_float(bits);  // best dist' = ||E||^2 - 2 z.E
    }
#pragma unroll
    for (int off = 32; off > 0; off >>= 1) lp += __shfl_down(lp, off, 64);
    if (lane == 0) s_wsum[wave] = lp;
    __syncthreads();
    if (t == 0) atomicAdd(loss, (s_wsum[0] + s_wsum[1]) * LOSS_SCALE);

    // gather-write z_q (STE forward == z_q), float4 coalesced, E is L2-hot
    const float4* E4 = (const float4*)E;
    float4* out4 = (float4*)(out + (size_t)row0 * DIM);
#pragma unroll
    for (int i = 0; i < (MTILE * DIM) / (256 * 4); ++i) {  // 16
        const int f = t + i * 256;
        const int r = f >> 5;  // 32 float4 per row
        const int d = f & 31;
        out4[f] = E4[(size_t)s_ind[r] * 32 + d];
    }
}

extern "C" void kernel_launch(void* const* d_in, const int* in_sizes, int n_in,
                              void* d_out, int out_size, void* d_ws, size_t ws_size,
                              hipStream_t stream) {
    const float* z = (const float*)d_in[0];  // [BN,128] fp32
    const float* E = (const float*)d_in[1];  // [1024,128] fp32
    float* out = (float*)d_out;              // [BN*128] z_q + [1] loss
    float* loss = out + (size_t)(out_size - 1);
    _Float16* Es = (_Float16*)d_ws;                              // 512 KB
    float* enorm = (float*)(Es + (size_t)NCODES * DIM * 2);      // 4 KB
    u64* winners = (u64*)(enorm + NCODES);                       // 512 KB
    int* tickets = (int*)(winners + 65536);                      // 2 KB
    const int BN = in_sizes[0] / DIM;

    prep_kernel<<<NCODES, 128, 0, stream>>>(E, Es, enorm, winners, tickets, loss);
    vq_kernel<<<(BN / MTILE) * NKB, 256, 0, stream>>>(z, Es, enorm, winners,
                                                      tickets, E, out, loss);
}

// Round 11
// 132.800 us; speedup vs baseline: 1.5724x; 1.5724x over previous
//
#include <hip/hip_runtime.h>
#include <hip/hip_bf16.h>
#include <cfloat>

// B=32, N=2048 -> BN=65536 rows, D=128, K=1024 codes
#define DIM 128
#define NCODES 1024
#define MTILE 128            // rows per block = 4 waves x 32 rows
#define ROWS_PER_WAVE 32
#define NSUB 2               // 16-row M-subtiles per wave
#define KSTEPS 4             // K=128 / 32
#define CODES_PER_STEP 64    // fat steps: r8/r10 showed ~2.2us/step-slot is
                             // FIXED overhead (barrier+vmcnt drain+ramp), so
                             // fewer steps wins. 16 steps vs r8's 32.
#define NSTEPS (NCODES / CODES_PER_STEP)  // 16
#define PART_HALVES 8192     // hi (or lo) halves per 64-code step (16 KB)
#define STEP_HALVES 16384    // hi+lo per step = 32 KB
#define LOSS_SCALE (12.5f / 8388608.0f)

typedef _Float16 f16x8 __attribute__((ext_vector_type(8)));
typedef float f32x4 __attribute__((ext_vector_type(4)));

// prep: E (fp32) -> f16 hi/lo split in MFMA-fragment chunk order (staging
// copies and ds_read_b128 fragment reads lane-consecutive = conflict-free);
// enorm = ||E_k||^2; block 0 zeroes loss.
__global__ __launch_bounds__(128) void prep_kernel(const float* __restrict__ E,
                                                   _Float16* __restrict__ Es,
                                                   float* __restrict__ enorm,
                                                   float* __restrict__ loss) {
    const int code = blockIdx.x;
    const int d = threadIdx.x;
    if (code == 0 && d == 0) *loss = 0.f;
    float e = E[code * DIM + d];
    _Float16 h = (_Float16)e;
    _Float16 l = (_Float16)(e - (float)h);
    const int st = code >> 6, u = (code >> 4) & 3, m16 = code & 15;
    const int ks = d >> 5, quad = (d >> 3) & 3, j = d & 7;
    const int chunk = ks * 256 + u * 64 + quad * 16 + m16;  // 1024 chunks/part
    const size_t base = (size_t)st * STEP_HALVES + (size_t)chunk * 8 + j;
    Es[base] = h;
    Es[base + PART_HALVES] = l;
    float sq = e * e;
#pragma unroll
    for (int off = 32; off > 0; off >>= 1) sq += __shfl_down(sq, off, 64);
    __shared__ float s2[2];
    if ((d & 63) == 0) s2[d >> 6] = sq;
    __syncthreads();
    if (d == 0) enorm[code] = s2[0] + s2[1];
}

// Fused MFMA dist + argmin + gather + loss, LDS-staged B, 64-code steps.
// r8/r10 post-mortem: per-step wall is ~constant (~2.2us/slot) independent of
// per-step work (24 vs 12 MFMAs/step both hit it); occupancy is pinned at
// 2 blocks/CU regardless of LDS (r10: 19.5 KB changed nothing). So: halve the
// step count by doubling codes/step. 2x32 KB dbuf + 4 KB enorm = 69 KB LDS
// (still 2 blocks/CU). Single kernel, full K per block (r10's K-split doubled
// z FETCH and bought nothing).
// r3 lesson: no runtime-indexed register arrays. r5: stay on (256,2).
__global__ __launch_bounds__(256, 2) void vq_kernel(const float* __restrict__ z,
                                                    const _Float16* __restrict__ Es,
                                                    const float* __restrict__ enorm,
                                                    const float* __restrict__ E,
                                                    float* __restrict__ out,
                                                    float* __restrict__ loss) {
    const int t = threadIdx.x;
    const int lane = t & 63;
    const int wave = t >> 6;     // row-wave: rows [wave*32, wave*32+32)
    const int m16 = lane & 15;   // A row within subtile / B,C code col
    const int quad = lane >> 4;  // k-group for A/B; row-group for C

    __shared__ _Float16 s_b[2][STEP_HALVES];  // 2 x 32 KB double buffer
    __shared__ float s_enorm[NCODES];         // 4 KB
    __shared__ float s_znorm[MTILE];
    __shared__ int s_ind[MTILE];
    __shared__ float s_wsum[4];

    for (int i = t; i < NCODES; i += 256) s_enorm[i] = enorm[i];

    // ---- A fragments: wave's 32 rows, K=128, scaled by -2, f16 hi/lo split.
    // A layout (16x16x32): lane holds A[m=lane&15][k=quad*8+j], j=0..7.
    f16x8 Ahi[NSUB][KSTEPS], Alo[NSUB][KSTEPS];
    float znp[NSUB] = {0.f, 0.f};
    const int rowbase = blockIdx.x * MTILE + wave * ROWS_PER_WAVE;
#pragma unroll
    for (int s = 0; s < NSUB; ++s) {
        const int row = rowbase + s * 16 + m16;
        const float* zp = z + (size_t)row * DIM + quad * 8;
#pragma unroll
        for (int ks = 0; ks < KSTEPS; ++ks) {
            float4 v0 = *(const float4*)(zp + ks * 32);
            float4 v1 = *(const float4*)(zp + ks * 32 + 4);
            float zv[8] = {v0.x, v0.y, v0.z, v0.w, v1.x, v1.y, v1.z, v1.w};
#pragma unroll
            for (int j = 0; j < 8; ++j) {
                znp[s] = fmaf(zv[j], zv[j], znp[s]);
                float tt = -2.f * zv[j];
                _Float16 h = (_Float16)tt;
                Ahi[s][ks][j] = h;
                Alo[s][ks][j] = (_Float16)(tt - (float)h);
            }
        }
    }
    // znorm per row -> LDS (consumed after loop; loop barriers order it)
#pragma unroll
    for (int s = 0; s < NSUB; ++s) {
        float v = znp[s];
        v += __shfl_xor(v, 16, 64);
        v += __shfl_xor(v, 32, 64);
        if (quad == 0) s_znorm[wave * ROWS_PER_WAVE + s * 16 + m16] = v;
    }

    float bestv[NSUB][4];
    int besti[NSUB][4];
#pragma unroll
    for (int s = 0; s < NSUB; ++s)
#pragma unroll
        for (int r = 0; r < 4; ++r) {
            bestv[s][r] = FLT_MAX;
            besti[s][r] = 0;
        }

    // Stage step ST's 32 KB tile: 2048 16B chunks; thread t copies chunks
    // {t, t+256, ..., t+1792}. Global contiguous (coalesced); LDS
    // lane-consecutive (conflict-free).
#define STAGE(ST, B)                                                 \
    {                                                                \
        const _Float16* src = Es + (size_t)(ST)*STEP_HALVES;         \
        _Pragma("unroll") for (int c = 0; c < 8; ++c) {              \
            const int idx = t + c * 256;                             \
            *(f16x8*)&s_b[B][(size_t)idx * 8] =                      \
                *(const f16x8*)(src + (size_t)idx * 8);              \
        }                                                            \
    }

    STAGE(0, 0)
    __syncthreads();

    int buf = 0;
    for (int st = 0; st < NSTEPS; ++st) {
        if (st + 1 < NSTEPS) STAGE(st + 1, buf ^ 1)  // overlap with compute
        const _Float16* bh = s_b[buf];
        const _Float16* bl = s_b[buf] + PART_HALVES;
#pragma unroll
        for (int u = 0; u < 4; ++u) {  // four 16-code subgroups
            f16x8 Bh[KSTEPS], Bl[KSTEPS];
#pragma unroll
            for (int ks = 0; ks < KSTEPS; ++ks) {
                const int chunk = ks * 256 + u * 64 + lane;  // lane-consecutive
                Bh[ks] = *(const f16x8*)(bh + (size_t)chunk * 8);
                Bl[ks] = *(const f16x8*)(bl + (size_t)chunk * 8);
            }
            f32x4 acc_hh[NSUB], acc_c[NSUB];
#pragma unroll
            for (int s = 0; s < NSUB; ++s) {
                acc_hh[s] = (f32x4){0.f, 0.f, 0.f, 0.f};
                acc_c[s] = (f32x4){0.f, 0.f, 0.f, 0.f};
            }
#pragma unroll
            for (int ks = 0; ks < KSTEPS; ++ks)
#pragma unroll
                for (int s = 0; s < NSUB; ++s) {
                    acc_c[s] = __builtin_amdgcn_mfma_f32_16x16x32_f16(Ahi[s][ks], Bl[ks], acc_c[s], 0, 0, 0);
                    acc_c[s] = __builtin_amdgcn_mfma_f32_16x16x32_f16(Alo[s][ks], Bh[ks], acc_c[s], 0, 0, 0);
                    acc_hh[s] = __builtin_amdgcn_mfma_f32_16x16x32_f16(Ahi[s][ks], Bh[ks], acc_hh[s], 0, 0, 0);
                }
            const int n = st * CODES_PER_STEP + u * 16 + m16;
            const float e = s_enorm[n];
            // C layout: col = lane&15 (code), row = quad*4 + r
#pragma unroll
            for (int s = 0; s < NSUB; ++s)
#pragma unroll
                for (int r = 0; r < 4; ++r) {
                    float d = (acc_hh[s][r] + acc_c[s][r]) + e;
                    if (d < bestv[s][r]) {  // strict <, ascending n => first-index
                        bestv[s][r] = d;
                        besti[s][r] = n;
                    }
                }
        }
        __syncthreads();  // staged st+1 visible; buf safe to overwrite at st+2
        buf ^= 1;
    }
#undef STAGE

    // ---- in-wave argmin across the 16 m16-lanes (lexicographic (v,i) ==
    // global first-index rule)
#pragma unroll
    for (int s = 0; s < NSUB; ++s)
#pragma unroll
        for (int r = 0; r < 4; ++r) {
            float v = bestv[s][r];
            int i = besti[s][r];
#pragma unroll
            for (int m = 1; m <= 8; m <<= 1) {
                float ov = __shfl_xor(v, m, 64);
                int oi = __shfl_xor(i, m, 64);
                if (ov < v || (ov == v && oi < i)) {
                    v = ov;
                    i = oi;
                }
            }
            bestv[s][r] = v;
            besti[s][r] = i;
        }

    float lp = 0.f;
    if (m16 == 0) {  // one winner lane per quad; owns rows quad*4+r (+s*16)
#pragma unroll
        for (int s = 0; s < NSUB; ++s)
#pragma unroll
            for (int r = 0; r < 4; ++r) {
                const int row = wave * ROWS_PER_WAVE + s * 16 + quad * 4 + r;
                s_ind[row] = besti[s][r];
                lp += s_znorm[row] + bestv[s][r];  // ||z-E||^2 = ||z||^2 + dist'
            }
    }
    lp += __shfl_xor(lp, 16, 64);  // lanes {0,16,32,48} hold partials
    lp += __shfl_xor(lp, 32, 64);
    if (lane == 0) s_wsum[wave] = lp;
    __syncthreads();
    if (t == 0)
        atomicAdd(loss, (s_wsum[0] + s_wsum[1] + s_wsum[2] + s_wsum[3]) * LOSS_SCALE);

    // ---- gather-write z_q (STE forward == z_q), float4 coalesced, E is L2-hot
    const float4* E4 = (const float4*)E;
    float4* out4 = (float4*)(out + (size_t)blockIdx.x * (MTILE * DIM));
#pragma unroll
    for (int i = 0; i < (MTILE * DIM) / (256 * 4); ++i) {
        const int f = t + i * 256;  // float4 index within tile
        const int r = f >> 5;       // 32 float4 per row
        const int d = f & 31;
        out4[f] = E4[(size_t)s_ind[r] * 32 + d];
    }
}

extern "C" void kernel_launch(void* const* d_in, const int* in_sizes, int n_in,
                              void* d_out, int out_size, void* d_ws, size_t ws_size,
                              hipStream_t stream) {
    const float* z = (const float*)d_in[0];  // [BN,128] fp32
    const float* E = (const float*)d_in[1];  // [1024,128] fp32
    float* out = (float*)d_out;              // [BN*128] z_q + [1] loss
    float* loss = out + (size_t)(out_size - 1);
    _Float16* Es = (_Float16*)d_ws;                       // 512 KB chunked hi/lo
    float* enorm = (float*)(Es + (size_t)NSTEPS * STEP_HALVES);  // 4 KB
    const int BN = in_sizes[0] / DIM;

    prep_kernel<<<NCODES, 128, 0, stream>>>(E, Es, enorm, loss);
    vq_kernel<<<BN / MTILE, 256, 0, stream>>>(z, Es, enorm, E, out, loss);
}